// Round 4
// baseline (284.983 us; speedup 1.0000x reference)
//
#include <hip/hip_runtime.h>
#include <stdint.h>

typedef _Float16 f16;
typedef __attribute__((ext_vector_type(8))) _Float16 f16x8;
typedef __attribute__((ext_vector_type(4))) _Float16 f16x4;
typedef __attribute__((ext_vector_type(4))) float f32x4;

typedef __attribute__((address_space(3))) uint32_t lds_u32;
typedef const __attribute__((address_space(1))) uint32_t glb_u32;

__device__ __forceinline__ void gload_lds16(const void* g, void* l) {
    // async global->LDS, 16B per lane; LDS dest = wave-uniform base + lane*16
    __builtin_amdgcn_global_load_lds((glb_u32*)g, (lds_u32*)l, 16, 0, 0);
}

// ============ 2-phase counted engine (dual weight GEMMs) ============
// BK=64, double-buffered LDS, stage(t+1) issued BEFORE ds_read/MFMA of t,
// exactly ONE vmcnt(0)+s_barrier per K-tile.
// LDS [rows][64] f16, 16B-slot XOR swizzle slot^=(row&7), both-sides.

template<int ROWS>
__device__ __forceinline__
void stage2(const f16* __restrict__ G, int ldg, f16* lds,
            int grow0, int k0, int tid)
{
    const int l = tid & 63, w = tid >> 6;
    #pragma unroll
    for (int q = 0; q < ROWS / 32; ++q) {
        const int r = q * 32 + w * 8 + (l >> 3);          // LDS/tile row
        const int csw = (((l & 7) ^ (r & 7)) << 3);       // inverse-swz col (f16)
        gload_lds16(G + (long long)(grow0 + r) * ldg + (k0 + csw),
                    lds + q * 2048 + w * 512);
    }
}

template<int OUT_MODE, int CAUSAL, int TM, int TN>
__device__ __forceinline__
void gemm2_body(const f16* __restrict__ A, const f16* __restrict__ B,
                const float* __restrict__ bias, void* __restrict__ Cv,
                int M, int N, int K,
                long long sAb, long long sBb, long long sCb, float scale,
                int bx, int by, int bzi)
{
    constexpr int IM = TM / 32;    // frags per wave (M)
    constexpr int JN = TN / 32;    // frags per wave (N)

    int mtile, n0;
    if (CAUSAL == 1) {
        int rem = bx, mi = 0;
        while (rem > mi) { rem -= mi + 1; ++mi; }
        mtile = mi;
        n0 = rem * TN;
    } else {
        mtile = by;
        n0 = bx * TN;
    }

    const int tid  = threadIdx.x;
    const int wave = tid >> 6;
    const int lane = tid & 63;
    const long long bz = bzi;
    A += bz * sAb;
    B += bz * sBb;

    __shared__ f16 As[2][TM * 64];
    __shared__ f16 Bs[2][TN * 64];

    const int fr  = lane & 15;
    const int hk  = lane >> 4;          // 16B slot group within K=64 (0..3)
    const int lsw = lane & 7;           // == (frag row)&7
    const int wm  = (wave >> 1) * (TM / 2);
    const int wn  = (wave & 1) * (TN / 2);

    const int npass = (CAUSAL == 2) ? 2 : 1;
    for (int pass = 0; pass < npass; ++pass) {
        const int mt = (CAUSAL == 2 && pass == 1) ? (M / TM - 1 - mtile) : mtile;
        const int m0 = mt * TM;
        const int Kend = (CAUSAL == 2) ? (m0 + TM) : K;

        f32x4 acc[IM][JN] = {};

        stage2<TM>(A, K, &As[0][0], m0, 0, tid);
        stage2<TN>(B, K, &Bs[0][0], n0, 0, tid);
        asm volatile("s_waitcnt vmcnt(0)" ::: "memory");
        __builtin_amdgcn_s_barrier();

        int cur = 0;
        for (int k0 = 0; k0 < Kend; k0 += 64) {
            if (k0 + 64 < Kend) {
                stage2<TM>(A, K, &As[cur ^ 1][0], m0, k0 + 64, tid);
                stage2<TN>(B, K, &Bs[cur ^ 1][0], n0, k0 + 64, tid);
            }

            f16x8 af[IM][2], bf[JN][2];
            #pragma unroll
            for (int i = 0; i < IM; ++i)
                #pragma unroll
                for (int kk = 0; kk < 2; ++kk)
                    af[i][kk] = *(const f16x8*)((const char*)&As[cur][0] +
                        ((wm + i * 16 + fr) << 7) +
                        ((((kk << 2) | hk) ^ lsw) << 4));
            #pragma unroll
            for (int j = 0; j < JN; ++j)
                #pragma unroll
                for (int kk = 0; kk < 2; ++kk)
                    bf[j][kk] = *(const f16x8*)((const char*)&Bs[cur][0] +
                        ((wn + j * 16 + fr) << 7) +
                        ((((kk << 2) | hk) ^ lsw) << 4));

            asm volatile("s_waitcnt lgkmcnt(0)" ::: "memory");
            __builtin_amdgcn_s_setprio(1);
            #pragma unroll
            for (int i = 0; i < IM; ++i)
                #pragma unroll
                for (int j = 0; j < JN; ++j)
                    #pragma unroll
                    for (int kk = 0; kk < 2; ++kk)
                        acc[i][j] = __builtin_amdgcn_mfma_f32_16x16x32_f16(
                            af[i][kk], bf[j][kk], acc[i][j], 0, 0, 0);
            __builtin_amdgcn_s_setprio(0);

            asm volatile("s_waitcnt vmcnt(0)" ::: "memory");
            __builtin_amdgcn_s_barrier();
            cur ^= 1;
        }

        const int cn = lane & 15;
        const int cm = (lane >> 4) * 4;
        #pragma unroll
        for (int j = 0; j < JN; ++j) {
            const int gn = n0 + wn + j * 16 + cn;
            #pragma unroll
            for (int i = 0; i < IM; ++i) {
                const int gm = m0 + wm + i * 16 + cm;
                if (OUT_MODE == 0) {
                    const float bv = bias ? bias[gn] : 0.f;
                    float* C = (float*)Cv + bz * sCb;
                    #pragma unroll
                    for (int r = 0; r < 4; ++r)
                        C[(long long)(gm + r) * N + gn] = acc[i][j][r] * scale + bv;
                } else {
                    const float bv = bias ? bias[(long long)bz * N + gn] : 0.f;
                    f16* C = (f16*)Cv + bz * sCb;
                    #pragma unroll
                    for (int r = 0; r < 4; ++r)
                        C[(long long)(gm + r) * N + gn] = (f16)(acc[i][j][r] * scale + bv);
                }
            }
        }
    }
}

// ============== R12: fused softmax+PV kernel ==============
// out[b,q,e] = sum_k softmax(Sc)[q,k] * Vt[e,k] + bo[e]
// A-path reg-staged: load Sc f16x8 (swizzled col), mask k>q, p=exp(s-mx)*inv,
// pack f16, ds_write to the same swizzled LDS slot gload would use.
// (mx, inv) precomputed per row by rowstat. Pb buffer eliminated.
// TM=128, TN=64, BK=64, diagonal-paired m-tiles (y and 15-y), 512 blocks.

__device__ __forceinline__
void pv_loadA(const f16* __restrict__ A, int lda, int m0, int k0, int tid,
              f16x8 va[4])
{
    const int l = tid & 63, w = tid >> 6;
    #pragma unroll
    for (int q = 0; q < 4; ++q) {
        const int r = q * 32 + w * 8 + (l >> 3);
        const int csw = (((l & 7) ^ (r & 7)) << 3);
        va[q] = *(const f16x8*)&A[(long long)(m0 + r) * lda + (k0 + csw)];
    }
}

__device__ __forceinline__
void pv_writeA(f16* lds, const f16x8 va[4], const float2 st[4],
               int m0, int k0, int tid)
{
    const int l = tid & 63, w = tid >> 6;
    #pragma unroll
    for (int q = 0; q < 4; ++q) {
        const int r = q * 32 + w * 8 + (l >> 3);
        const int qrow = m0 + r;
        const int csw = (((l & 7) ^ (r & 7)) << 3);
        f16x8 o;
        #pragma unroll
        for (int e = 0; e < 8; ++e) {
            const int k = k0 + csw + e;
            const float p = (k <= qrow)
                ? __expf((float)va[q][e] - st[q].x) * st[q].y : 0.f;
            o[e] = (f16)p;
        }
        *(f16x8*)&lds[q * 2048 + w * 512 + l * 8] = o;
    }
}

__global__ __launch_bounds__(256, 3)
void pv_fused(const f16* __restrict__ Sc, const f16* __restrict__ Vt,
              const float2* __restrict__ rs, const float* __restrict__ bo,
              float* __restrict__ out)
{
    constexpr int S = 2048, D = 1024;
    constexpr int TM = 128, TN = 64, IM = 4, JN = 2;
    const int tid  = threadIdx.x;
    const int wave = tid >> 6;
    const int lane = tid & 63;
    const long long bz = blockIdx.z;
    const f16* A  = Sc + bz * ((long long)S * S);
    const f16* Bp = Vt + bz * ((long long)D * S);
    const float2* rsb = rs + bz * S;
    const int n0 = blockIdx.x * TN;
    const int mtile = blockIdx.y;

    __shared__ f16 As[2][TM * 64];
    __shared__ f16 Bs[2][TN * 64];

    const int fr  = lane & 15;
    const int hk  = lane >> 4;
    const int lsw = lane & 7;
    const int wm  = (wave >> 1) * (TM / 2);
    const int wn  = (wave & 1) * (TN / 2);
    const int w8  = (tid >> 6) * 8 + ((tid & 63) >> 3);   // staging row in 32-group

    for (int pass = 0; pass < 2; ++pass) {
        const int mt = (pass == 1) ? (S / TM - 1 - mtile) : mtile;
        const int m0 = mt * TM;
        const int Kend = m0 + TM;

        float2 st[4];
        #pragma unroll
        for (int q = 0; q < 4; ++q) st[q] = rsb[m0 + q * 32 + w8];

        f32x4 acc[IM][JN] = {};
        f16x8 va[4];

        // prologue: tile 0
        pv_loadA(A, S, m0, 0, tid, va);
        stage2<TN>(Bp, S, &Bs[0][0], n0, 0, tid);
        asm volatile("s_waitcnt vmcnt(2)" ::: "memory");   // A regs ready
        pv_writeA(&As[0][0], va, st, m0, 0, tid);
        asm volatile("s_waitcnt vmcnt(0) lgkmcnt(0)" ::: "memory");
        __builtin_amdgcn_s_barrier();

        int cur = 0;
        for (int k0 = 0; k0 < Kend; k0 += 64) {
            const bool nxt = (k0 + 64 < Kend);
            if (nxt) {
                pv_loadA(A, S, m0, k0 + 64, tid, va);          // 4 loads
                stage2<TN>(Bp, S, &Bs[cur ^ 1][0], n0, k0 + 64, tid);  // 2 loads
            }

            f16x8 af[IM][2], bf[JN][2];
            #pragma unroll
            for (int i = 0; i < IM; ++i)
                #pragma unroll
                for (int kk = 0; kk < 2; ++kk)
                    af[i][kk] = *(const f16x8*)((const char*)&As[cur][0] +
                        ((wm + i * 16 + fr) << 7) +
                        ((((kk << 2) | hk) ^ lsw) << 4));
            #pragma unroll
            for (int j = 0; j < JN; ++j)
                #pragma unroll
                for (int kk = 0; kk < 2; ++kk)
                    bf[j][kk] = *(const f16x8*)((const char*)&Bs[cur][0] +
                        ((wn + j * 16 + fr) << 7) +
                        ((((kk << 2) | hk) ^ lsw) << 4));

            asm volatile("s_waitcnt lgkmcnt(0)" ::: "memory");
            __builtin_amdgcn_s_setprio(1);
            #pragma unroll
            for (int i = 0; i < IM; ++i)
                #pragma unroll
                for (int j = 0; j < JN; ++j)
                    #pragma unroll
                    for (int kk = 0; kk < 2; ++kk)
                        acc[i][j] = __builtin_amdgcn_mfma_f32_16x16x32_f16(
                            af[i][kk], bf[j][kk], acc[i][j], 0, 0, 0);
            __builtin_amdgcn_s_setprio(0);

            if (nxt) {
                asm volatile("s_waitcnt vmcnt(2)" ::: "memory");  // A regs ready
                pv_writeA(&As[cur ^ 1][0], va, st, m0, k0 + 64, tid);
            }
            asm volatile("s_waitcnt vmcnt(0) lgkmcnt(0)" ::: "memory");
            __builtin_amdgcn_s_barrier();
            cur ^= 1;
        }

        // epilogue: fp32 out + bo
        const int cn = lane & 15;
        const int cm = (lane >> 4) * 4;
        float* C = out + bz * ((long long)S * D);
        #pragma unroll
        for (int j = 0; j < JN; ++j) {
            const int gn = n0 + wn + j * 16 + cn;
            const float bv = bo[gn];
            #pragma unroll
            for (int i = 0; i < IM; ++i) {
                const int gm = m0 + wm + i * 16 + cm;
                #pragma unroll
                for (int r = 0; r < 4; ++r)
                    C[(long long)(gm + r) * D + gn] = acc[i][j][r] + bv;
            }
        }
    }
}

// ============== 256x256 4-phase counted engine (proj + scores) ==============
__device__ __forceinline__
void stage_half(const f16* __restrict__ G, int ldg, f16* lds_half,
                int grow0, int k0, int tid)
{
    const int lr  = tid >> 3;                               // local row 0..63
    const int csw = ((tid & 7) * 8) ^ ((lr & 7) << 3);      // inverse-swizzled col
    gload_lds16(G + (long long)(grow0 + lr) * ldg + (k0 + csw),
                lds_half + ((tid >> 6) << 9));
    gload_lds16(G + (long long)(grow0 + 64 + lr) * ldg + (k0 + csw),
                lds_half + 4096 + ((tid >> 6) << 9));
}

template<int MODE>
__global__ __launch_bounds__(512, 2)
void gemm256_4ph(const f16* __restrict__ A, const f16* __restrict__ B,
                 const float* __restrict__ bias, const float* __restrict__ bias2,
                 f16* __restrict__ C0, f16* __restrict__ C1,
                 int M, int N, int K,
                 long long sAb, long long sBb, long long sCb, float scale)
{
    __shared__ f16 As[2][16384];   // [buf][256 rows][64 cols]
    __shared__ f16 Bs[2][16384];

    const int nwg  = gridDim.x;
    const int orig = blockIdx.x;
    const int swz  = (orig & 7) * (nwg >> 3) + (orig >> 3);

    int m0, n0;
    long long bz = 0;
    if (MODE == 1) {
        const int nr  = M >> 8;
        const int per = nr * (nr + 1) / 2;
        bz = swz / per;
        int rem = swz - (int)bz * per, mi = 0;
        while (rem > mi) { rem -= mi + 1; ++mi; }
        m0 = mi << 8;
        n0 = rem << 8;
    } else {
        const int ntn = N >> 8;
        const int mt = swz / ntn, nt = swz - mt * ntn;
        m0 = mt << 8;
        n0 = nt << 8;
    }
    A += bz * sAb;
    B += bz * sBb;

    const int tid  = threadIdx.x;
    const int lane = tid & 63;
    const int wave = tid >> 6;
    const int wm = (wave >> 2) << 7;
    const int wn = (wave & 3) << 6;
    const int fr  = lane & 15;
    const int hk  = lane >> 4;
    const int lsw = lane & 7;
    const int nkt = K >> 6;

    f32x4 acc[8][4] = {};
    f16x8 bf[4][2];

    stage_half(A, K, &As[0][0],    m0,       0, tid);
    stage_half(A, K, &As[0][8192], m0 + 128, 0, tid);
    stage_half(B, K, &Bs[0][0],    n0,       0, tid);
    stage_half(B, K, &Bs[0][8192], n0 + 128, 0, tid);
    if (nkt > 1) {
        stage_half(B, K, &Bs[1][0],    n0,       64, tid);
        stage_half(B, K, &Bs[1][8192], n0 + 128, 64, tid);
        asm volatile("s_waitcnt vmcnt(4)" ::: "memory");
    } else {
        asm volatile("s_waitcnt vmcnt(0)" ::: "memory");
    }
    __builtin_amdgcn_s_barrier();

    for (int t = 0; t < nkt; ++t) {
        const f16* Ab = As[t & 1];
        const f16* Bb = Bs[t & 1];
        #pragma unroll
        for (int p = 0; p < 4; ++p) {
            if (p == 0) {
                #pragma unroll
                for (int j = 0; j < 4; ++j)
                    #pragma unroll
                    for (int kk = 0; kk < 2; ++kk)
                        bf[j][kk] = *(const f16x8*)((const char*)Bb +
                            ((wn + j * 16 + fr) << 7) +
                            ((((kk << 2) | hk) ^ lsw) << 4));
            }
            f16x8 af[2][2];
            #pragma unroll
            for (int ii = 0; ii < 2; ++ii)
                #pragma unroll
                for (int kk = 0; kk < 2; ++kk)
                    af[ii][kk] = *(const f16x8*)((const char*)Ab +
                        ((wm + (2 * p + ii) * 16 + fr) << 7) +
                        ((((kk << 2) | hk) ^ lsw) << 4));

            if (p == 0 && t + 1 < nkt)
                stage_half(A, K, &As[(t + 1) & 1][0],    m0,       (t + 1) << 6, tid);
            if (p == 1 && t + 1 < nkt)
                stage_half(A, K, &As[(t + 1) & 1][8192], m0 + 128, (t + 1) << 6, tid);
            if (p == 2 && t + 2 < nkt)
                stage_half(B, K, &Bs[t & 1][0],          n0,       (t + 2) << 6, tid);
            if (p == 3 && t + 2 < nkt)
                stage_half(B, K, &Bs[t & 1][8192],       n0 + 128, (t + 2) << 6, tid);

            if (p == 0) asm volatile("s_waitcnt lgkmcnt(8)" ::: "memory");
            __builtin_amdgcn_s_barrier();
            asm volatile("s_waitcnt lgkmcnt(0)" ::: "memory");
            __builtin_amdgcn_s_setprio(1);
            #pragma unroll
            for (int ii = 0; ii < 2; ++ii)
                #pragma unroll
                for (int j = 0; j < 4; ++j)
                    #pragma unroll
                    for (int kk = 0; kk < 2; ++kk)
                        acc[2 * p + ii][j] = __builtin_amdgcn_mfma_f32_16x16x32_f16(
                            af[ii][kk], bf[j][kk], acc[2 * p + ii][j], 0, 0, 0);
            __builtin_amdgcn_s_setprio(0);
            if (p == 3) {
                if (t + 2 < nkt) asm volatile("s_waitcnt vmcnt(4)" ::: "memory");
                else             asm volatile("s_waitcnt vmcnt(0)" ::: "memory");
            }
            __builtin_amdgcn_s_barrier();
        }
    }

    const int cn  = lane & 15;
    const int cm4 = (lane >> 4) * 4;
    #pragma unroll
    for (int j = 0; j < 4; ++j) {
        const int gn = n0 + wn + j * 16 + cn;
        if (MODE == 3) {
            const int sel = gn >> 10;
            const int nn  = gn & 1023;
            #pragma unroll
            for (int i = 0; i < 8; ++i) {
                const int gm = m0 + wm + i * 16 + cm4;
                if (sel == 0) {
                    #pragma unroll
                    for (int r = 0; r < 4; ++r)
                        C0[(long long)(gm + r) * 1024 + nn] = (f16)acc[i][j][r];
                } else {
                    const float bb = bias2[nn];
                    const int b = gm >> 11, s = gm & 2047;
                    f16x4 pk;
                    #pragma unroll
                    for (int r = 0; r < 4; ++r)
                        pk[r] = (f16)(acc[i][j][r] + bb);
                    *(f16x4*)&C1[(long long)b * 2097152 + (long long)nn * 2048 + s] = pk;
                }
            }
        } else {
            const float cbv = bias ? bias[bz * N + gn] : 0.f;
            f16* Cc = C0 + bz * sCb;
            #pragma unroll
            for (int i = 0; i < 8; ++i) {
                const int gm = m0 + wm + i * 16 + cm4;
                #pragma unroll
                for (int r = 0; r < 4; ++r)
                    Cc[(long long)(gm + r) * N + gn] = (f16)(acc[i][j][r] * scale + cbv);
            }
        }
    }
}

// ---- prep: all input-only transforms in ONE launch ----
__global__ __launch_bounds__(256)
void prep(const float* __restrict__ x,  const float* __restrict__ Wq,
          const float* __restrict__ bq, const float* __restrict__ Wk,
          const float* __restrict__ Wv, const float* __restrict__ bv,
          const float* __restrict__ Wo,
          f16* __restrict__ xb,  f16* __restrict__ Wqf, f16* __restrict__ Wkf,
          f16* __restrict__ Wvf, f16* __restrict__ Wot,
          float* __restrict__ bvo, float* __restrict__ wvec)
{
    __shared__ f16 tile[32][33];
    __shared__ float red[4][64];
    const int t = threadIdx.x;
    int id = blockIdx.x;

    if (id < 8192) {                       // cast x -> xb (f16)
        const int i = (id * 256 + t) * 4;
        const float4 v = *(const float4*)&x[i];
        f16x4 o; o[0]=(f16)v.x; o[1]=(f16)v.y; o[2]=(f16)v.z; o[3]=(f16)v.w;
        *(f16x4*)&xb[i] = o;
        return;
    }
    id -= 8192;
    if (id < 3072) {                       // cast Wq/Wk/Wv (f16)
        const float* src = (id < 1024) ? Wq : (id < 2048) ? Wk : Wv;
        f16* dst = (id < 1024) ? Wqf : (id < 2048) ? Wkf : Wvf;
        const int i = ((id & 1023) * 256 + t) * 4;
        const float4 v = *(const float4*)&src[i];
        f16x4 o; o[0]=(f16)v.x; o[1]=(f16)v.y; o[2]=(f16)v.z; o[3]=(f16)v.w;
        *(f16x4*)&dst[i] = o;
        return;
    }
    id -= 3072;
    if (id < 1024) {                       // Wot[e][k] = (f16) Wo[k][e]
        const int bx = (id & 31) * 32, by = (id >> 5) * 32;
        const int tx = t & 31, ty = t >> 5;
        #pragma unroll
        for (int i = 0; i < 32; i += 8)
            tile[ty + i][tx] = (f16)Wo[(long long)(by + ty + i) * 1024 + (bx + tx)];
        __syncthreads();
        #pragma unroll
        for (int i = 0; i < 32; i += 8)
            Wot[(long long)(bx + ty + i) * 1024 + (by + tx)] = tile[tx][ty + i];
        return;
    }
    id -= 1024;
    if (id < 16) {                         // bvo[e] = sum_k bv[k] Wo[k][e]
        const int e0 = id * 64;
        const int wave = t >> 6, lane = t & 63;
        float a0 = 0.f, a1 = 0.f, a2 = 0.f, a3 = 0.f;
        for (int i = 0; i < 256; i += 4) {
            const int k = wave * 256 + i;
            a0 += bv[k]     * Wo[(long long)k * 1024 + e0 + lane];
            a1 += bv[k + 1] * Wo[(long long)(k + 1) * 1024 + e0 + lane];
            a2 += bv[k + 2] * Wo[(long long)(k + 2) * 1024 + e0 + lane];
            a3 += bv[k + 3] * Wo[(long long)(k + 3) * 1024 + e0 + lane];
        }
        red[wave][lane] = (a0 + a1) + (a2 + a3);
        __syncthreads();
        if (wave == 0)
            bvo[e0 + lane] = red[0][lane] + red[1][lane] + red[2][lane] + red[3][lane];
        return;
    }
    id -= 16;
    {                                      // wvec[d] = (Wk[d,:].bq)/8
        const int row = id * 4 + (t >> 6);
        const int lane = t & 63;
        const float* src = Wk + (long long)row * 1024;
        float a = 0.f;
        #pragma unroll
        for (int tt = 0; tt < 16; ++tt) a += src[lane + 64 * tt] * bq[lane + 64 * tt];
        #pragma unroll
        for (int o = 32; o > 0; o >>= 1) a += __shfl_down(a, o);
        if (lane == 0) wvec[row] = a * 0.125f;
    }
}

// ---- dual: both weight-product GEMMs + cvec in ONE launch ----
__global__ __launch_bounds__(256, 2)
void dual_weights_cvec(const f16* __restrict__ Wkf, const f16* __restrict__ Wqf,
                       const f16* __restrict__ Wot, const f16* __restrict__ Wvf,
                       f16* __restrict__ Wcat2,
                       const f16* __restrict__ xb, const float* __restrict__ wvec,
                       float* __restrict__ cbias)
{
    if (blockIdx.z == 2) {
        const int flat = blockIdx.y * 8 + blockIdx.x;   // 0..63
        const int wave = threadIdx.x >> 6, lane = threadIdx.x & 63;
        #pragma unroll 4
        for (int rr = 0; rr < 32; ++rr) {
            const int row = (flat * 4 + wave) * 32 + rr;   // covers 0..8191
            const f16* src = xb + (long long)row * 1024;
            float a = 0.f;
            #pragma unroll
            for (int tt = 0; tt < 16; ++tt)
                a += (float)src[lane + 64 * tt] * wvec[lane + 64 * tt];
            #pragma unroll
            for (int o = 32; o > 0; o >>= 1) a += __shfl_down(a, o);
            if (lane == 0) cbias[row] = a;
        }
        return;
    }
    const f16* Ax = (blockIdx.z == 0) ? Wkf : Wot;
    const f16* Bx = (blockIdx.z == 0) ? Wqf : Wvf;
    f16* Cx = Wcat2 + (long long)blockIdx.z * 1024 * 1024;
    gemm2_body<1, 0, 128, 128>(Ax, Bx, nullptr, Cx,
                               1024, 1024, 1024, 0, 0, 0, 1.f,
                               blockIdx.x, blockIdx.y, 0);
}

// ---- rowstat: per score row (b,q): mx = max_{k<=q} Sc, inv = 1/sum exp ----
// 1 wave per row, 4 rows per block; butterfly reduce, no LDS.
__global__ __launch_bounds__(256)
void rowstat(const f16* __restrict__ Sc, float2* __restrict__ rs, int S)
{
    const int wave = threadIdx.x >> 6, lane = threadIdx.x & 63;
    const long long row = (long long)blockIdx.x * 4 + wave;
    const int q = (int)(row & (S - 1));          // S power of 2
    const f16* src = Sc + row * S;

    float v[32];
    float mx = -3.0e38f;
    #pragma unroll
    for (int i = 0; i < 4; ++i) {
        const int c0 = i * 512 + lane * 8;
        f16x8 vv = {};
        if (c0 <= q) vv = *(const f16x8*)&src[c0];
        #pragma unroll
        for (int e = 0; e < 8; ++e) {
            const int k = c0 + e;
            v[i * 8 + e] = (float)vv[e];
            if (k <= q) mx = fmaxf(mx, v[i * 8 + e]);
        }
    }
    #pragma unroll
    for (int o = 32; o > 0; o >>= 1) mx = fmaxf(mx, __shfl_xor(mx, o));

    float sum = 0.f;
    #pragma unroll
    for (int i = 0; i < 4; ++i) {
        const int c0 = i * 512 + lane * 8;
        #pragma unroll
        for (int e = 0; e < 8; ++e) {
            const int k = c0 + e;
            if (k <= q) sum += __expf(v[i * 8 + e] - mx);
        }
    }
    #pragma unroll
    for (int o = 32; o > 0; o >>= 1) sum += __shfl_xor(sum, o);

    if (lane == 0) rs[row] = make_float2(mx, 1.f / sum);
}

extern "C" void kernel_launch(void* const* d_in, const int* in_sizes, int n_in,
                              void* d_out, int out_size, void* d_ws, size_t ws_size,
                              hipStream_t stream)
{
    const float* x  = (const float*)d_in[0];
    const float* Wq = (const float*)d_in[1];
    const float* bq = (const float*)d_in[2];
    const float* Wk = (const float*)d_in[3];
    // bk (d_in[4]) unused: Q.bk^T is row-constant -> softmax-invariant.
    const float* Wv = (const float*)d_in[5];
    const float* bv = (const float*)d_in[6];
    const float* Wo = (const float*)d_in[7];
    const float* bo = (const float*)d_in[8];
    float* out = (float*)d_out;

    const int B = 4, S = 2048, D = 1024;
    const long long SD  = (long long)S * D;
    const long long SS  = (long long)S * S;
    const long long BSD = (long long)B * SD;
    const int MS = B * S;

    char* p = (char*)d_ws;
    f16*   xb    = (f16*)p;  p += BSD * 2;
    f16*   Wqf   = (f16*)p;  p += (long long)D * D * 2;
    f16*   Wkf   = (f16*)p;  p += (long long)D * D * 2;
    f16*   Wvf   = (f16*)p;  p += (long long)D * D * 2;
    f16*   Wot   = (f16*)p;  p += (long long)D * D * 2;
    f16*   Wcat2 = (f16*)p;  p += 2LL * D * D * 2;        // [WqkT; WvoT]
    float* bvo   = (float*)p; p += D * 4;
    float* wvec  = (float*)p; p += D * 4;
    float* cbias = (float*)p; p += (long long)MS * 4;
    f16*   Qh    = (f16*)p;  p += BSD * 2;
    f16*   Vt    = (f16*)p;  p += BSD * 2;                // Vo^T [B][1024][2048]
    f16*   Sc    = (f16*)p;  p += (long long)B * SS * 2;
    float2* rs   = (float2*)p; p += (long long)MS * 8;    // (mx, 1/sum) per row

    dim3 blk(256);

    // 1) prep: all casts/transposes/small reductions, one launch
    prep<<<dim3(12560), blk, 0, stream>>>(x, Wq, bq, Wk, Wv, bv, Wo,
                                          xb, Wqf, Wkf, Wvf, Wot, bvo, wvec);

    // 2) weight-product GEMMs (128^2 2-phase) + cvec, one launch
    dual_weights_cvec<<<dim3(8, 8, 3), blk, 0, stream>>>(Wkf, Wqf, Wot, Wvf,
                                                         Wcat2, xb, wvec, cbias);

    // 3) fused projection: x @ [WqkT; WvoT]^T -> Qh flat; Vo^T batched (+bvo)
    dim3 gproj((MS / 256) * (2 * D / 256));
    gemm256_4ph<3><<<gproj, dim3(512), 0, stream>>>(xb, Wcat2, nullptr, bvo,
                                                    Qh, Vt,
                                                    MS, 2 * D, D, 0, 0, 0, 1.f);

    // 4) scores = (Qh x^T)/8 + cbias[k]: 256^2 4-phase, triangular-256
    dim3 gsc(144);
    gemm256_4ph<1><<<gsc, dim3(512), 0, stream>>>(Qh, xb, cbias, nullptr,
                                                  Sc, nullptr,
                                                  S, S, D, SD, SD, SS, 0.125f);

    // 5) rowstat: per-row (max, 1/sum) -- softmax folded into PV
    rowstat<<<dim3((unsigned)(B * S / 4)), blk, 0, stream>>>(Sc, rs, S);

    // 6) fused softmax+PV: out = softmax(Sc) @ Vo + bo, diagonal-paired
    dim3 gpv(D / 64, S / 128 / 2, B);
    pv_fused<<<gpv, blk, 0, stream>>>(Sc, Vt, rs, bo, out);
}

// Round 5
// 244.969 us; speedup vs baseline: 1.1633x; 1.1633x over previous
//
#include <hip/hip_runtime.h>
#include <stdint.h>

typedef _Float16 f16;
typedef __attribute__((ext_vector_type(8))) _Float16 f16x8;
typedef __attribute__((ext_vector_type(4))) _Float16 f16x4;
typedef __attribute__((ext_vector_type(4))) float f32x4;

typedef __attribute__((address_space(3))) uint32_t lds_u32;
typedef const __attribute__((address_space(1))) uint32_t glb_u32;

__device__ __forceinline__ void gload_lds16(const void* g, void* l) {
    // async global->LDS, 16B per lane; LDS dest = wave-uniform base + lane*16
    __builtin_amdgcn_global_load_lds((glb_u32*)g, (lds_u32*)l, 16, 0, 0);
}

// ============ 2-phase counted engine (PV + dual weight GEMMs) ============
// BK=64, double-buffered LDS, stage(t+1) issued BEFORE ds_read/MFMA of t,
// exactly ONE vmcnt(0)+s_barrier per K-tile.
// LDS [rows][64] f16, 16B-slot XOR swizzle slot^=(row&7), both-sides.

template<int ROWS>
__device__ __forceinline__
void stage2(const f16* __restrict__ G, int ldg, f16* lds,
            int grow0, int k0, int tid)
{
    const int l = tid & 63, w = tid >> 6;
    #pragma unroll
    for (int q = 0; q < ROWS / 32; ++q) {
        const int r = q * 32 + w * 8 + (l >> 3);          // LDS/tile row
        const int csw = (((l & 7) ^ (r & 7)) << 3);       // inverse-swz col (f16)
        gload_lds16(G + (long long)(grow0 + r) * ldg + (k0 + csw),
                    lds + q * 2048 + w * 512);
    }
}

template<int OUT_MODE, int CAUSAL, int TM, int TN>
__device__ __forceinline__
void gemm2_body(const f16* __restrict__ A, const f16* __restrict__ B,
                const float* __restrict__ bias, void* __restrict__ Cv,
                int M, int N, int K,
                long long sAb, long long sBb, long long sCb, float scale,
                int bx, int by, int bzi)
{
    constexpr int IM = TM / 32;    // frags per wave (M)
    constexpr int JN = TN / 32;    // frags per wave (N)

    int mtile, n0;
    if (CAUSAL == 1) {
        int rem = bx, mi = 0;
        while (rem > mi) { rem -= mi + 1; ++mi; }
        mtile = mi;
        n0 = rem * TN;
    } else {
        mtile = by;
        n0 = bx * TN;
    }

    const int tid  = threadIdx.x;
    const int wave = tid >> 6;
    const int lane = tid & 63;
    const long long bz = bzi;
    A += bz * sAb;
    B += bz * sBb;

    __shared__ f16 As[2][TM * 64];
    __shared__ f16 Bs[2][TN * 64];

    const int fr  = lane & 15;
    const int hk  = lane >> 4;          // 16B slot group within K=64 (0..3)
    const int lsw = lane & 7;           // == (frag row)&7
    const int wm  = (wave >> 1) * (TM / 2);
    const int wn  = (wave & 1) * (TN / 2);

    const int npass = (CAUSAL == 2) ? 2 : 1;
    for (int pass = 0; pass < npass; ++pass) {
        const int mt = (CAUSAL == 2 && pass == 1) ? (M / TM - 1 - mtile) : mtile;
        const int m0 = mt * TM;
        const int Kend = (CAUSAL == 2) ? (m0 + TM) : K;

        f32x4 acc[IM][JN] = {};

        stage2<TM>(A, K, &As[0][0], m0, 0, tid);
        stage2<TN>(B, K, &Bs[0][0], n0, 0, tid);
        asm volatile("s_waitcnt vmcnt(0)" ::: "memory");
        __builtin_amdgcn_s_barrier();

        int cur = 0;
        for (int k0 = 0; k0 < Kend; k0 += 64) {
            if (k0 + 64 < Kend) {
                stage2<TM>(A, K, &As[cur ^ 1][0], m0, k0 + 64, tid);
                stage2<TN>(B, K, &Bs[cur ^ 1][0], n0, k0 + 64, tid);
            }

            f16x8 af[IM][2], bf[JN][2];
            #pragma unroll
            for (int i = 0; i < IM; ++i)
                #pragma unroll
                for (int kk = 0; kk < 2; ++kk)
                    af[i][kk] = *(const f16x8*)((const char*)&As[cur][0] +
                        ((wm + i * 16 + fr) << 7) +
                        ((((kk << 2) | hk) ^ lsw) << 4));
            #pragma unroll
            for (int j = 0; j < JN; ++j)
                #pragma unroll
                for (int kk = 0; kk < 2; ++kk)
                    bf[j][kk] = *(const f16x8*)((const char*)&Bs[cur][0] +
                        ((wn + j * 16 + fr) << 7) +
                        ((((kk << 2) | hk) ^ lsw) << 4));

            asm volatile("s_waitcnt lgkmcnt(0)" ::: "memory");
            __builtin_amdgcn_s_setprio(1);
            #pragma unroll
            for (int i = 0; i < IM; ++i)
                #pragma unroll
                for (int j = 0; j < JN; ++j)
                    #pragma unroll
                    for (int kk = 0; kk < 2; ++kk)
                        acc[i][j] = __builtin_amdgcn_mfma_f32_16x16x32_f16(
                            af[i][kk], bf[j][kk], acc[i][j], 0, 0, 0);
            __builtin_amdgcn_s_setprio(0);

            asm volatile("s_waitcnt vmcnt(0)" ::: "memory");
            __builtin_amdgcn_s_barrier();
            cur ^= 1;
        }

        const int cn = lane & 15;
        const int cm = (lane >> 4) * 4;
        #pragma unroll
        for (int j = 0; j < JN; ++j) {
            const int gn = n0 + wn + j * 16 + cn;
            #pragma unroll
            for (int i = 0; i < IM; ++i) {
                const int gm = m0 + wm + i * 16 + cm;
                if (OUT_MODE == 0) {
                    const float bv = bias ? bias[gn] : 0.f;
                    float* C = (float*)Cv + bz * sCb;
                    #pragma unroll
                    for (int r = 0; r < 4; ++r)
                        C[(long long)(gm + r) * N + gn] = acc[i][j][r] * scale + bv;
                } else {
                    const float bv = bias ? bias[(long long)bz * N + gn] : 0.f;
                    f16* C = (f16*)Cv + bz * sCb;
                    #pragma unroll
                    for (int r = 0; r < 4; ++r)
                        C[(long long)(gm + r) * N + gn] = (f16)(acc[i][j][r] * scale + bv);
                }
            }
        }
    }
}

template<int OUT_MODE, int CAUSAL, int TM, int TN>
__global__ __launch_bounds__(256, 2)
void gemm2_bt(const f16* __restrict__ A, const f16* __restrict__ B,
              const float* __restrict__ bias, void* __restrict__ Cv,
              int M, int N, int K,
              long long sAb, long long sBb, long long sCb, float scale)
{
    gemm2_body<OUT_MODE, CAUSAL, TM, TN>(A, B, bias, Cv, M, N, K,
                                         sAb, sBb, sCb, scale,
                                         blockIdx.x, blockIdx.y, blockIdx.z);
}

// ============== 256x256 4-phase counted engine (proj + scores) ==============
// R13: single 128KiB LDS block (As/Bs overlay); MODE 3's Vt epilogue stages
// the 256x256 output tile through LDS (XOR-swizzled 8B slots) so global
// stores are 512B-contiguous per wave (was: 8B scattered at 4KB stride,
// WRITE_SIZE 53MB vs 33.5MB ideal).

__device__ __forceinline__
void stage_half(const f16* __restrict__ G, int ldg, f16* lds_half,
                int grow0, int k0, int tid)
{
    const int lr  = tid >> 3;                               // local row 0..63
    const int csw = ((tid & 7) * 8) ^ ((lr & 7) << 3);      // inverse-swizzled col
    gload_lds16(G + (long long)(grow0 + lr) * ldg + (k0 + csw),
                lds_half + ((tid >> 6) << 9));
    gload_lds16(G + (long long)(grow0 + 64 + lr) * ldg + (k0 + csw),
                lds_half + 4096 + ((tid >> 6) << 9));
}

template<int MODE>
__global__ __launch_bounds__(512, 2)
void gemm256_4ph(const f16* __restrict__ A, const f16* __restrict__ B,
                 const float* __restrict__ bias, const float* __restrict__ bias2,
                 f16* __restrict__ C0, f16* __restrict__ C1,
                 int M, int N, int K,
                 long long sAb, long long sBb, long long sCb, float scale)
{
    __shared__ f16 lds[65536];     // [As0|As1|Bs0|Bs1] 16384 f16 each

    const int nwg  = gridDim.x;
    const int orig = blockIdx.x;
    const int swz  = (orig & 7) * (nwg >> 3) + (orig >> 3);

    int m0, n0;
    long long bz = 0;
    if (MODE == 1) {
        const int nr  = M >> 8;
        const int per = nr * (nr + 1) / 2;
        bz = swz / per;
        int rem = swz - (int)bz * per, mi = 0;
        while (rem > mi) { rem -= mi + 1; ++mi; }
        m0 = mi << 8;
        n0 = rem << 8;
    } else {
        const int ntn = N >> 8;
        const int mt = swz / ntn, nt = swz - mt * ntn;
        m0 = mt << 8;
        n0 = nt << 8;
    }
    A += bz * sAb;
    B += bz * sBb;

    const int tid  = threadIdx.x;
    const int lane = tid & 63;
    const int wave = tid >> 6;
    const int wm = (wave >> 2) << 7;
    const int wn = (wave & 3) << 6;
    const int fr  = lane & 15;
    const int hk  = lane >> 4;
    const int lsw = lane & 7;
    const int nkt = K >> 6;

    f32x4 acc[8][4] = {};
    f16x8 bf[4][2];

    stage_half(A, K, lds,         m0,       0, tid);
    stage_half(A, K, lds + 8192,  m0 + 128, 0, tid);
    stage_half(B, K, lds + 32768, n0,       0, tid);
    stage_half(B, K, lds + 40960, n0 + 128, 0, tid);
    if (nkt > 1) {
        stage_half(B, K, lds + 49152, n0,       64, tid);
        stage_half(B, K, lds + 57344, n0 + 128, 64, tid);
        asm volatile("s_waitcnt vmcnt(4)" ::: "memory");
    } else {
        asm volatile("s_waitcnt vmcnt(0)" ::: "memory");
    }
    __builtin_amdgcn_s_barrier();

    for (int t = 0; t < nkt; ++t) {
        const f16* Ab = lds + (t & 1) * 16384;
        const f16* Bb = lds + 32768 + (t & 1) * 16384;
        #pragma unroll
        for (int p = 0; p < 4; ++p) {
            if (p == 0) {
                #pragma unroll
                for (int j = 0; j < 4; ++j)
                    #pragma unroll
                    for (int kk = 0; kk < 2; ++kk)
                        bf[j][kk] = *(const f16x8*)((const char*)Bb +
                            ((wn + j * 16 + fr) << 7) +
                            ((((kk << 2) | hk) ^ lsw) << 4));
            }
            f16x8 af[2][2];
            #pragma unroll
            for (int ii = 0; ii < 2; ++ii)
                #pragma unroll
                for (int kk = 0; kk < 2; ++kk)
                    af[ii][kk] = *(const f16x8*)((const char*)Ab +
                        ((wm + (2 * p + ii) * 16 + fr) << 7) +
                        ((((kk << 2) | hk) ^ lsw) << 4));

            if (p == 0 && t + 1 < nkt)
                stage_half(A, K, lds + ((t + 1) & 1) * 16384,        m0,       (t + 1) << 6, tid);
            if (p == 1 && t + 1 < nkt)
                stage_half(A, K, lds + ((t + 1) & 1) * 16384 + 8192, m0 + 128, (t + 1) << 6, tid);
            if (p == 2 && t + 2 < nkt)
                stage_half(B, K, lds + 32768 + (t & 1) * 16384,        n0,       (t + 2) << 6, tid);
            if (p == 3 && t + 2 < nkt)
                stage_half(B, K, lds + 32768 + (t & 1) * 16384 + 8192, n0 + 128, (t + 2) << 6, tid);

            if (p == 0) asm volatile("s_waitcnt lgkmcnt(8)" ::: "memory");
            __builtin_amdgcn_s_barrier();
            asm volatile("s_waitcnt lgkmcnt(0)" ::: "memory");
            __builtin_amdgcn_s_setprio(1);
            #pragma unroll
            for (int ii = 0; ii < 2; ++ii)
                #pragma unroll
                for (int j = 0; j < 4; ++j)
                    #pragma unroll
                    for (int kk = 0; kk < 2; ++kk)
                        acc[2 * p + ii][j] = __builtin_amdgcn_mfma_f32_16x16x32_f16(
                            af[ii][kk], bf[j][kk], acc[2 * p + ii][j], 0, 0, 0);
            __builtin_amdgcn_s_setprio(0);
            if (p == 3) {
                if (t + 2 < nkt) asm volatile("s_waitcnt vmcnt(4)" ::: "memory");
                else             asm volatile("s_waitcnt vmcnt(0)" ::: "memory");
            }
            __builtin_amdgcn_s_barrier();
        }
    }

    const int cn  = lane & 15;
    const int cm4 = (lane >> 4) * 4;

    if (MODE == 3 && (n0 >> 10)) {
        // ---- Vt epilogue: LDS-transposed, coalesced 512B stores ----
        // K-loop's trailing barrier proved all LDS reads done; reuse lds.
        const int nn0 = n0 & 1023;
        const int b   = m0 >> 11, s0v = m0 & 2047;
        #pragma unroll
        for (int j = 0; j < 4; ++j) {
            const int nn_l = wn + j * 16 + cn;              // 0..255
            const float bb = bias2[nn0 + nn_l];
            const int X = (nn_l & 7) << 4;                  // 8B-slot XOR swizzle
            #pragma unroll
            for (int i = 0; i < 8; ++i) {
                const int s_l = wm + i * 16 + cm4;          // 0..252, mult of 4
                f16x4 pk;
                #pragma unroll
                for (int r = 0; r < 4; ++r)
                    pk[r] = (f16)(acc[i][j][r] + bb);
                *(f16x4*)((char*)lds + nn_l * 512 + ((s_l * 2) ^ X)) = pk;
            }
        }
        __syncthreads();
        #pragma unroll 4
        for (int rr = 0; rr < 32; ++rr) {
            const int nn_l = rr * 8 + wave;
            const int X = (nn_l & 7) << 4;
            const f16x4 v = *(const f16x4*)((const char*)lds + nn_l * 512 + ((lane * 8) ^ X));
            *(f16x4*)&C1[(long long)b * 2097152 + (long long)(nn0 + nn_l) * 2048 + s0v + lane * 4] = v;
        }
        return;
    }

    #pragma unroll
    for (int j = 0; j < 4; ++j) {
        const int gn = n0 + wn + j * 16 + cn;
        if (MODE == 3) {                 // Qh flat f16 [M,1024]
            const int nn = gn & 1023;
            #pragma unroll
            for (int i = 0; i < 8; ++i) {
                const int gm = m0 + wm + i * 16 + cm4;
                #pragma unroll
                for (int r = 0; r < 4; ++r)
                    C0[(long long)(gm + r) * 1024 + nn] = (f16)acc[i][j][r];
            }
        } else {                         // MODE 1: f16 [M,N]+scale+col-bias
            const float cbv = bias ? bias[bz * N + gn] : 0.f;
            f16* Cc = C0 + bz * sCb;
            #pragma unroll
            for (int i = 0; i < 8; ++i) {
                const int gm = m0 + wm + i * 16 + cm4;
                #pragma unroll
                for (int r = 0; r < 4; ++r)
                    Cc[(long long)(gm + r) * N + gn] = (f16)(acc[i][j][r] * scale + cbv);
            }
        }
    }
}

// ---- prep: all input-only transforms in ONE launch ----
__global__ __launch_bounds__(256)
void prep(const float* __restrict__ x,  const float* __restrict__ Wq,
          const float* __restrict__ bq, const float* __restrict__ Wk,
          const float* __restrict__ Wv, const float* __restrict__ bv,
          const float* __restrict__ Wo,
          f16* __restrict__ xb,  f16* __restrict__ Wqf, f16* __restrict__ Wkf,
          f16* __restrict__ Wvf, f16* __restrict__ Wot,
          float* __restrict__ bvo, float* __restrict__ wvec)
{
    __shared__ f16 tile[32][33];
    __shared__ float red[4][64];
    const int t = threadIdx.x;
    int id = blockIdx.x;

    if (id < 8192) {                       // cast x -> xb (f16)
        const int i = (id * 256 + t) * 4;
        const float4 v = *(const float4*)&x[i];
        f16x4 o; o[0]=(f16)v.x; o[1]=(f16)v.y; o[2]=(f16)v.z; o[3]=(f16)v.w;
        *(f16x4*)&xb[i] = o;
        return;
    }
    id -= 8192;
    if (id < 3072) {                       // cast Wq/Wk/Wv (f16)
        const float* src = (id < 1024) ? Wq : (id < 2048) ? Wk : Wv;
        f16* dst = (id < 1024) ? Wqf : (id < 2048) ? Wkf : Wvf;
        const int i = ((id & 1023) * 256 + t) * 4;
        const float4 v = *(const float4*)&src[i];
        f16x4 o; o[0]=(f16)v.x; o[1]=(f16)v.y; o[2]=(f16)v.z; o[3]=(f16)v.w;
        *(f16x4*)&dst[i] = o;
        return;
    }
    id -= 3072;
    if (id < 1024) {                       // Wot[e][k] = (f16) Wo[k][e]
        const int bx = (id & 31) * 32, by = (id >> 5) * 32;
        const int tx = t & 31, ty = t >> 5;
        #pragma unroll
        for (int i = 0; i < 32; i += 8)
            tile[ty + i][tx] = (f16)Wo[(long long)(by + ty + i) * 1024 + (bx + tx)];
        __syncthreads();
        #pragma unroll
        for (int i = 0; i < 32; i += 8)
            Wot[(long long)(bx + ty + i) * 1024 + (by + tx)] = tile[tx][ty + i];
        return;
    }
    id -= 1024;
    if (id < 16) {                         // bvo[e] = sum_k bv[k] Wo[k][e]
        const int e0 = id * 64;
        const int wave = t >> 6, lane = t & 63;
        float a0 = 0.f, a1 = 0.f, a2 = 0.f, a3 = 0.f;
        for (int i = 0; i < 256; i += 4) {
            const int k = wave * 256 + i;
            a0 += bv[k]     * Wo[(long long)k * 1024 + e0 + lane];
            a1 += bv[k + 1] * Wo[(long long)(k + 1) * 1024 + e0 + lane];
            a2 += bv[k + 2] * Wo[(long long)(k + 2) * 1024 + e0 + lane];
            a3 += bv[k + 3] * Wo[(long long)(k + 3) * 1024 + e0 + lane];
        }
        red[wave][lane] = (a0 + a1) + (a2 + a3);
        __syncthreads();
        if (wave == 0)
            bvo[e0 + lane] = red[0][lane] + red[1][lane] + red[2][lane] + red[3][lane];
        return;
    }
    id -= 16;
    {                                      // wvec[d] = (Wk[d,:].bq)/8
        const int row = id * 4 + (t >> 6);
        const int lane = t & 63;
        const float* src = Wk + (long long)row * 1024;
        float a = 0.f;
        #pragma unroll
        for (int tt = 0; tt < 16; ++tt) a += src[lane + 64 * tt] * bq[lane + 64 * tt];
        #pragma unroll
        for (int o = 32; o > 0; o >>= 1) a += __shfl_down(a, o);
        if (lane == 0) wvec[row] = a * 0.125f;
    }
}

// ---- dual: both weight-product GEMMs + cvec in ONE launch ----
__global__ __launch_bounds__(256, 2)
void dual_weights_cvec(const f16* __restrict__ Wkf, const f16* __restrict__ Wqf,
                       const f16* __restrict__ Wot, const f16* __restrict__ Wvf,
                       f16* __restrict__ Wcat2,
                       const f16* __restrict__ xb, const float* __restrict__ wvec,
                       float* __restrict__ cbias)
{
    if (blockIdx.z == 2) {
        const int flat = blockIdx.y * 8 + blockIdx.x;   // 0..63
        const int wave = threadIdx.x >> 6, lane = threadIdx.x & 63;
        #pragma unroll 4
        for (int rr = 0; rr < 32; ++rr) {
            const int row = (flat * 4 + wave) * 32 + rr;   // covers 0..8191
            const f16* src = xb + (long long)row * 1024;
            float a = 0.f;
            #pragma unroll
            for (int tt = 0; tt < 16; ++tt)
                a += (float)src[lane + 64 * tt] * wvec[lane + 64 * tt];
            #pragma unroll
            for (int o = 32; o > 0; o >>= 1) a += __shfl_down(a, o);
            if (lane == 0) cbias[row] = a;
        }
        return;
    }
    const f16* Ax = (blockIdx.z == 0) ? Wkf : Wot;
    const f16* Bx = (blockIdx.z == 0) ? Wqf : Wvf;
    f16* Cx = Wcat2 + (long long)blockIdx.z * 1024 * 1024;
    gemm2_body<1, 0, 128, 128>(Ax, Bx, nullptr, Cx,
                               1024, 1024, 1024, 0, 0, 0, 1.f,
                               blockIdx.x, blockIdx.y, 0);
}

// One block per score row (b,q). Predicated 16B loads skip masked chunks.
// Writes only up to the next 128 boundary (exactly what PV reads).
__global__ __launch_bounds__(256)
void softmax_causal(const f16* __restrict__ Sc, f16* __restrict__ P, int S)
{
    const long long row = blockIdx.x;
    const int q = (int)(row % S);
    const f16* src = Sc + row * S;
    f16* dst = P + row * S;
    const int t = threadIdx.x;
    __shared__ float redm[4], reds[4];

    f16x8 vv = {};
    if (t * 8 <= q) vv = *(const f16x8*)&src[t * 8];
    float v[8];
    float mx = -3.0e38f;
    #pragma unroll
    for (int i = 0; i < 8; ++i) {
        const int k = t * 8 + i;
        v[i] = (float)vv[i];
        if (k <= q) mx = fmaxf(mx, v[i]);
    }
    #pragma unroll
    for (int o = 32; o > 0; o >>= 1) mx = fmaxf(mx, __shfl_down(mx, o));
    if ((t & 63) == 0) redm[t >> 6] = mx;
    __syncthreads();
    mx = fmaxf(fmaxf(redm[0], redm[1]), fmaxf(redm[2], redm[3]));

    float sum = 0.f;
    #pragma unroll
    for (int i = 0; i < 8; ++i) {
        const int k = t * 8 + i;
        v[i] = (k <= q) ? __expf(v[i] - mx) : 0.f;
        sum += v[i];
    }
    #pragma unroll
    for (int o = 32; o > 0; o >>= 1) sum += __shfl_down(sum, o);
    if ((t & 63) == 0) reds[t >> 6] = sum;
    __syncthreads();
    sum = reds[0] + reds[1] + reds[2] + reds[3];
    const float inv = 1.f / sum;
    const int kend = ((q >> 7) + 1) << 7;   // PV reads k < kend only
    if (t * 8 < kend) {
        f16x8 ov;
        #pragma unroll
        for (int i = 0; i < 8; ++i) ov[i] = (f16)(v[i] * inv);
        *(f16x8*)&dst[t * 8] = ov;
    }
}

extern "C" void kernel_launch(void* const* d_in, const int* in_sizes, int n_in,
                              void* d_out, int out_size, void* d_ws, size_t ws_size,
                              hipStream_t stream)
{
    const float* x  = (const float*)d_in[0];
    const float* Wq = (const float*)d_in[1];
    const float* bq = (const float*)d_in[2];
    const float* Wk = (const float*)d_in[3];
    // bk (d_in[4]) unused: Q.bk^T is row-constant -> softmax-invariant.
    const float* Wv = (const float*)d_in[5];
    const float* bv = (const float*)d_in[6];
    const float* Wo = (const float*)d_in[7];
    const float* bo = (const float*)d_in[8];
    float* out = (float*)d_out;

    const int B = 4, S = 2048, D = 1024;
    const long long SD  = (long long)S * D;
    const long long SS  = (long long)S * S;
    const long long BSD = (long long)B * SD;
    const int MS = B * S;

    char* p = (char*)d_ws;
    f16*   xb    = (f16*)p;  p += BSD * 2;
    f16*   Wqf   = (f16*)p;  p += (long long)D * D * 2;
    f16*   Wkf   = (f16*)p;  p += (long long)D * D * 2;
    f16*   Wvf   = (f16*)p;  p += (long long)D * D * 2;
    f16*   Wot   = (f16*)p;  p += (long long)D * D * 2;
    f16*   Wcat2 = (f16*)p;  p += 2LL * D * D * 2;        // [WqkT; WvoT]
    float* bvo   = (float*)p; p += D * 4;
    float* wvec  = (float*)p; p += D * 4;
    float* cbias = (float*)p; p += (long long)MS * 4;
    f16*   Qh    = (f16*)p;  p += BSD * 2;
    f16*   Vt    = (f16*)p;  p += BSD * 2;                // Vo^T [B][1024][2048]
    f16*   Sc    = (f16*)p;  p += (long long)B * SS * 2;
    f16*   Pb    = (f16*)p;  p += (long long)B * SS * 2;

    dim3 blk(256);

    // 1) prep: all casts/transposes/small reductions, one launch
    prep<<<dim3(12560), blk, 0, stream>>>(x, Wq, bq, Wk, Wv, bv, Wo,
                                          xb, Wqf, Wkf, Wvf, Wot, bvo, wvec);

    // 2) weight-product GEMMs (128^2 2-phase) + cvec, one launch
    dual_weights_cvec<<<dim3(8, 8, 3), blk, 0, stream>>>(Wkf, Wqf, Wot, Wvf,
                                                         Wcat2, xb, wvec, cbias);

    // 3) fused projection: x @ [WqkT; WvoT]^T -> Qh flat; Vo^T batched (+bvo)
    //    R13: coalesced Vt epilogue via LDS transpose.
    dim3 gproj((MS / 256) * (2 * D / 256));
    gemm256_4ph<3><<<gproj, dim3(512), 0, stream>>>(xb, Wcat2, nullptr, bvo,
                                                    Qh, Vt,
                                                    MS, 2 * D, D, 0, 0, 0, 1.f);

    // 4) scores = (Qh x^T)/8 + cbias[k]: 256^2 4-phase, triangular-256
    dim3 gsc(144);
    gemm256_4ph<1><<<gsc, dim3(512), 0, stream>>>(Qh, xb, cbias, nullptr,
                                                  Sc, nullptr,
                                                  S, S, D, SD, SD, SS, 0.125f);

    // 5) causal softmax -> P (f16), predicated loads, 128-boundary writes
    softmax_causal<<<dim3((unsigned)(B * S)), blk, 0, stream>>>(Sc, Pb, S);

    // 6) out = P @ Vo + bo (fp32 final), diagonal-paired, 2-phase engine
    dim3 gpv(D / 64, S / 128 / 2, B);
    gemm2_bt<0, 2, 128, 64><<<gpv, blk, 0, stream>>>(Pb, Vt, bo, out,
                                                     S, D, S, SS, SD, SD, 1.f);
}